// Round 2
// baseline (1143.748 us; speedup 1.0000x reference)
//
#include <hip/hip_runtime.h>
#include <hip/hip_bf16.h>

// Problem constants
#define BATCH 2
#define SEQ   2048
#define HID_  2048
#define NH_   16
#define HD_   128

typedef __bf16 bf16x8 __attribute__((ext_vector_type(8)));
typedef float  f32x4  __attribute__((ext_vector_type(4)));

__device__ __forceinline__ unsigned short f32_to_bf16(float f) {
    unsigned int u = __builtin_bit_cast(unsigned int, f);
    unsigned int r = (u + 0x7fffu + ((u >> 16) & 1u)) >> 16;
    return (unsigned short)r;
}

// ---------------------------------------------------------------------------
// fp32 -> bf16 conversion, 4 elements / thread
// ---------------------------------------------------------------------------
__global__ void cvt_f32_bf16(const float* __restrict__ in,
                             unsigned short* __restrict__ out, int n4) {
    int i = blockIdx.x * blockDim.x + threadIdx.x;
    if (i >= n4) return;
    float4 a = reinterpret_cast<const float4*>(in)[i];
    ushort4 o;
    o.x = f32_to_bf16(a.x);
    o.y = f32_to_bf16(a.y);
    o.z = f32_to_bf16(a.z);
    o.w = f32_to_bf16(a.w);
    reinterpret_cast<ushort4*>(out)[i] = o;
}

// ---------------------------------------------------------------------------
// GEMM: C[M,N] = A[M,K] * B[N,K]^T + bias[N]
// A, B bf16 row-major (K contiguous).  MODE: 0 = bf16 row-major out,
// 1 = bf16 V^T out (b,h,d,s), 2 = fp32 row-major out.
// Block 256 = 4 waves; tile 128x128; wave tile 64x64 (4x4 of 16x16 frags).
// ---------------------------------------------------------------------------
enum { OUT_BF16 = 0, OUT_VT = 1, OUT_F32 = 2 };

template <int MODE>
__global__ __launch_bounds__(256)
void gemm_bt(const unsigned short* __restrict__ A,
             const unsigned short* __restrict__ B,
             const float* __restrict__ bias,
             void* __restrict__ Cout,
             int M, int N, int K) {
    const int tid  = threadIdx.x;
    const int lane = tid & 63;
    const int wid  = tid >> 6;          // 0..3
    const int wr   = wid >> 1;          // 0..1
    const int wc   = wid & 1;           // 0..1
    const int l16  = lane & 15;
    const int l4   = lane >> 4;         // 0..3

    const int row0 = blockIdx.y * 128 + wr * 64;
    const int col0 = blockIdx.x * 128 + wc * 64;

    f32x4 acc[4][4] = {};

    const unsigned short* Abase = A + (size_t)(row0 + l16) * K + l4 * 8;
    const unsigned short* Bbase = B + (size_t)(col0 + l16) * K + l4 * 8;

    for (int k0 = 0; k0 < K; k0 += 32) {
        bf16x8 af[4], bfr[4];
#pragma unroll
        for (int i = 0; i < 4; ++i)
            af[i] = *reinterpret_cast<const bf16x8*>(Abase + (size_t)i * 16 * K + k0);
#pragma unroll
        for (int j = 0; j < 4; ++j)
            bfr[j] = *reinterpret_cast<const bf16x8*>(Bbase + (size_t)j * 16 * K + k0);
#pragma unroll
        for (int i = 0; i < 4; ++i)
#pragma unroll
            for (int j = 0; j < 4; ++j)
                acc[i][j] = __builtin_amdgcn_mfma_f32_16x16x32_bf16(
                    af[i], bfr[j], acc[i][j], 0, 0, 0);
    }

    // Epilogue. C/D frag layout (verified): col = lane&15, row = (lane>>4)*4+reg
#pragma unroll
    for (int j = 0; j < 4; ++j) {
        const int col = col0 + j * 16 + l16;
        const float bv = bias[col];
#pragma unroll
        for (int i = 0; i < 4; ++i) {
#pragma unroll
            for (int r = 0; r < 4; ++r) {
                const int row = row0 + i * 16 + l4 * 4 + r;
                const float v = acc[i][j][r] + bv;
                if (MODE == OUT_BF16) {
                    ((unsigned short*)Cout)[(size_t)row * N + col] = f32_to_bf16(v);
                } else if (MODE == OUT_F32) {
                    ((float*)Cout)[(size_t)row * N + col] = v;
                } else {  // OUT_VT: row=(b,s), col=(h,d) -> Vt[((b*NH+h)*HD+d)*SEQ+s]
                    const int b = row >> 11, s = row & (SEQ - 1);
                    const int h = col >> 7,  d = col & (HD_ - 1);
                    ((unsigned short*)Cout)[((size_t)((b * NH_ + h) * HD_ + d)) * SEQ + s] =
                        f32_to_bf16(v);
                }
            }
        }
    }
}

// ---------------------------------------------------------------------------
// Causal flash attention.
// Q,K: (B*S, HID) bf16 row-major, head h at cols [h*128, h*128+128).
// Vt:  (B*NH*HD, S) bf16 row-major (s contiguous).
// O:   (B*S, HID) bf16 row-major.
// Grid: (S/64 q-tiles, B*NH). Block 256 = 4 waves; wave w owns q rows
// [qt*64 + w*16, +16). Waves are fully independent (no block barrier).
// ---------------------------------------------------------------------------
__global__ __launch_bounds__(256)
void attn_fwd(const unsigned short* __restrict__ Qm,
              const unsigned short* __restrict__ Km,
              const unsigned short* __restrict__ Vt,
              unsigned short* __restrict__ Om) {
    const int tid  = threadIdx.x;
    const int lane = tid & 63;
    const int wq   = tid >> 6;
    const int l16  = lane & 15;
    const int l4   = lane >> 4;

    const int qt = blockIdx.x;
    const int bh = blockIdx.y;          // b*NH + h
    const int b  = bh >> 4;
    const int h  = bh & (NH_ - 1);

    const int qbase = qt * 64 + wq * 16;

    __shared__ unsigned short plds[4][16][64];   // per-wave private P tile

    // Q fragments: rows qbase+l16, d-block kb*32 + l4*8
    const unsigned short* Qbase =
        Qm + ((size_t)(b * SEQ + qbase + l16)) * HID_ + h * HD_ + l4 * 8;
    bf16x8 qf[4];
#pragma unroll
    for (int kb = 0; kb < 4; ++kb)
        qf[kb] = *reinterpret_cast<const bf16x8*>(Qbase + kb * 32);

    float mrow[4], lrow[4];
#pragma unroll
    for (int r = 0; r < 4; ++r) { mrow[r] = -__builtin_inff(); lrow[r] = 0.f; }
    f32x4 acc[8] = {};

    const float scale = 0.08838834764831845f;  // 1/sqrt(128)
    const int qmax   = qbase + 15;
    const int ntiles = qmax / 64 + 1;

    const unsigned short* Kbh = Km + ((size_t)b * SEQ) * HID_ + h * HD_;
    const unsigned short* Vbh = Vt + (size_t)bh * HD_ * SEQ;

    for (int t = 0; t < ntiles; ++t) {
        const int kv0 = t * 64;

        // ---- scores: S[16 q][64 kv]  (4 column tiles) ----
        f32x4 sc[4];
#pragma unroll
        for (int ct = 0; ct < 4; ++ct) {
            f32x4 c = {};
            const unsigned short* Kp =
                Kbh + (size_t)(kv0 + ct * 16 + l16) * HID_ + l4 * 8;
#pragma unroll
            for (int kb = 0; kb < 4; ++kb) {
                bf16x8 kf = *reinterpret_cast<const bf16x8*>(Kp + kb * 32);
                c = __builtin_amdgcn_mfma_f32_16x16x32_bf16(qf[kb], kf, c, 0, 0, 0);
            }
            sc[ct] = c;
        }

        // ---- scale + causal mask ----
#pragma unroll
        for (int ct = 0; ct < 4; ++ct) {
            const int col = kv0 + ct * 16 + l16;
#pragma unroll
            for (int r = 0; r < 4; ++r) {
                float v = sc[ct][r] * scale;
                const int qrow = qbase + l4 * 4 + r;
                if (col > qrow) v = -__builtin_inff();
                sc[ct][r] = v;
            }
        }

        // ---- online softmax (row stats across 16-lane group) ----
        float tmax[4];
#pragma unroll
        for (int r = 0; r < 4; ++r) {
            float v = fmaxf(fmaxf(sc[0][r], sc[1][r]), fmaxf(sc[2][r], sc[3][r]));
#pragma unroll
            for (int off = 8; off >= 1; off >>= 1)
                v = fmaxf(v, __shfl_xor(v, off, 64));
            tmax[r] = v;
        }

        float alpha[4], rs[4];
#pragma unroll
        for (int r = 0; r < 4; ++r) {
            const float mn = fmaxf(mrow[r], tmax[r]);
            alpha[r] = __expf(mrow[r] - mn);   // expf(-inf)=0 on first tile
            mrow[r] = mn;
            rs[r] = 0.f;
        }

#pragma unroll
        for (int ct = 0; ct < 4; ++ct) {
#pragma unroll
            for (int r = 0; r < 4; ++r) {
                const float p = __expf(sc[ct][r] - mrow[r]);  // masked -> 0
                rs[r] += p;
                plds[wq][l4 * 4 + r][ct * 16 + l16] = f32_to_bf16(p);
            }
        }

#pragma unroll
        for (int r = 0; r < 4; ++r) {
#pragma unroll
            for (int off = 8; off >= 1; off >>= 1)
                rs[r] += __shfl_xor(rs[r], off, 64);
            lrow[r] = lrow[r] * alpha[r] + rs[r];
        }

        // ---- rescale O accumulator ----
#pragma unroll
        for (int dt = 0; dt < 8; ++dt)
#pragma unroll
            for (int r = 0; r < 4; ++r)
                acc[dt][r] *= alpha[r];

        // ---- PV: O += P[16x64] * V[64x128] ----
        asm volatile("s_waitcnt lgkmcnt(0)" ::: "memory");
        bf16x8 pf[2];
#pragma unroll
        for (int ks = 0; ks < 2; ++ks)
            pf[ks] = *reinterpret_cast<const bf16x8*>(&plds[wq][l16][ks * 32 + l4 * 8]);
#pragma unroll
        for (int dt = 0; dt < 8; ++dt) {
            const unsigned short* Vp = Vbh + (size_t)(dt * 16 + l16) * SEQ + kv0 + l4 * 8;
#pragma unroll
            for (int ks = 0; ks < 2; ++ks) {
                bf16x8 vf = *reinterpret_cast<const bf16x8*>(Vp + ks * 32);
                acc[dt] = __builtin_amdgcn_mfma_f32_16x16x32_bf16(pf[ks], vf, acc[dt], 0, 0, 0);
            }
        }
    }

    // ---- epilogue: O row-major bf16 at (b, q, h*128 + d) ----
    unsigned short* Ob = Om + ((size_t)(b * SEQ + qbase)) * HID_ + h * HD_;
#pragma unroll
    for (int dt = 0; dt < 8; ++dt) {
#pragma unroll
        for (int r = 0; r < 4; ++r) {
            const int qrow = l4 * 4 + r;
            const float v = acc[dt][r] / lrow[r];
            Ob[(size_t)qrow * HID_ + dt * 16 + l16] = f32_to_bf16(v);
        }
    }
}

// ---------------------------------------------------------------------------
extern "C" void kernel_launch(void* const* d_in, const int* in_sizes, int n_in,
                              void* d_out, int out_size, void* d_ws, size_t ws_size,
                              hipStream_t stream) {
    const float* X  = (const float*)d_in[0];
    const float* Wq = (const float*)d_in[1];
    const float* bq = (const float*)d_in[2];
    const float* Wk = (const float*)d_in[3];
    const float* bk = (const float*)d_in[4];
    const float* Wv = (const float*)d_in[5];
    const float* bv = (const float*)d_in[6];
    const float* Wo = (const float*)d_in[7];
    const float* bo = (const float*)d_in[8];
    float* out = (float*)d_out;

    const size_t MK = (size_t)BATCH * SEQ * HID_;   // 8388608
    const size_t WK = (size_t)HID_ * HID_;          // 4194304

    unsigned short* ws  = (unsigned short*)d_ws;
    unsigned short* Xb  = ws;
    unsigned short* Wqb = Xb  + MK;
    unsigned short* Wkb = Wqb + WK;
    unsigned short* Wvb = Wkb + WK;
    unsigned short* Wob = Wvb + WK;
    unsigned short* Qb  = Wob + WK;
    unsigned short* Kb  = Qb  + MK;
    unsigned short* Vtb = Kb  + MK;
    unsigned short* AOb = Vtb + MK;

    auto cvt = [&](const float* src, unsigned short* dst, size_t n) {
        int n4 = (int)(n / 4);
        cvt_f32_bf16<<<(n4 + 255) / 256, 256, 0, stream>>>(src, dst, n4);
    };
    cvt(X,  Xb,  MK);
    cvt(Wq, Wqb, WK);
    cvt(Wk, Wkb, WK);
    cvt(Wv, Wvb, WK);
    cvt(Wo, Wob, WK);

    const int M = BATCH * SEQ;   // 4096
    dim3 g(HID_ / 128, M / 128); // (16, 32)

    gemm_bt<OUT_BF16><<<g, 256, 0, stream>>>(Xb, Wqb, bq, Qb,  M, HID_, HID_);
    gemm_bt<OUT_BF16><<<g, 256, 0, stream>>>(Xb, Wkb, bk, Kb,  M, HID_, HID_);
    gemm_bt<OUT_VT>  <<<g, 256, 0, stream>>>(Xb, Wvb, bv, Vtb, M, HID_, HID_);

    attn_fwd<<<dim3(SEQ / 64, BATCH * NH_), 256, 0, stream>>>(Qb, Kb, Vtb, AOb);

    gemm_bt<OUT_F32><<<g, 256, 0, stream>>>(AOb, Wob, bo, out, M, HID_, HID_);
}

// Round 3
// 778.165 us; speedup vs baseline: 1.4698x; 1.4698x over previous
//
#include <hip/hip_runtime.h>
#include <hip/hip_bf16.h>

// Problem constants
#define BATCH 2
#define SEQ   2048
#define HID_  2048
#define NH_   16
#define HD_   128

typedef __bf16 bf16x8 __attribute__((ext_vector_type(8)));
typedef float  f32x4  __attribute__((ext_vector_type(4)));

__device__ __forceinline__ unsigned short f32_to_bf16(float f) {
    unsigned int u = __builtin_bit_cast(unsigned int, f);
    unsigned int r = (u + 0x7fffu + ((u >> 16) & 1u)) >> 16;
    return (unsigned short)r;
}

// async global->LDS, 16 bytes per lane. lds must be the WAVE-UNIFORM base;
// HW writes lane i at lds + i*16. g is the per-lane global source.
__device__ __forceinline__ void gld_lds16(void* lds, const void* g) {
    __builtin_amdgcn_global_load_lds(
        (const __attribute__((address_space(1))) unsigned int*)g,
        (__attribute__((address_space(3))) unsigned int*)lds, 16, 0, 0);
}

// ---------------------------------------------------------------------------
// fp32 -> bf16 conversion, 4 elements / thread
// ---------------------------------------------------------------------------
__global__ void cvt_f32_bf16(const float* __restrict__ in,
                             unsigned short* __restrict__ out, int n4) {
    int i = blockIdx.x * blockDim.x + threadIdx.x;
    if (i >= n4) return;
    float4 a = reinterpret_cast<const float4*>(in)[i];
    ushort4 o;
    o.x = f32_to_bf16(a.x);
    o.y = f32_to_bf16(a.y);
    o.z = f32_to_bf16(a.z);
    o.w = f32_to_bf16(a.w);
    reinterpret_cast<ushort4*>(out)[i] = o;
}

// ---------------------------------------------------------------------------
// GEMM: C[M,N] = A[M,K] * B[N,K]^T + bias[N]  (m97 structure: 128x128 tile,
// BK=32, LDS staged via global_load_lds width 16, 2 barriers / K-step).
// A, B bf16 row-major (K contiguous).  MODE: 0 = bf16 row-major out,
// 1 = bf16 V^T out (b,h,d,s), 2 = fp32 row-major out.
// Block 256 = 4 waves; wave tile 64x64 (4x4 of 16x16 frags).
// ---------------------------------------------------------------------------
enum { OUT_BF16 = 0, OUT_VT = 1, OUT_F32 = 2 };

template <int MODE>
__global__ __launch_bounds__(256)
void gemm_bt(const unsigned short* __restrict__ A,
             const unsigned short* __restrict__ B,
             const float* __restrict__ bias,
             void* __restrict__ Cout,
             int M, int N, int K) {
    const int tid  = threadIdx.x;
    const int lane = tid & 63;
    const int wid  = tid >> 6;          // 0..3
    const int wr   = wid >> 1;          // 0..1
    const int wc   = wid & 1;           // 0..1
    const int l16  = lane & 15;
    const int l4   = lane >> 4;         // 0..3

    const int row0 = blockIdx.y * 128;  // block A rows
    const int col0 = blockIdx.x * 128;  // block B rows (C cols)

    __shared__ unsigned short As[128 * 32];
    __shared__ unsigned short Bs[128 * 32];

    f32x4 acc[4][4] = {};

    // staging geometry: inst i in {0,1}; t2 = i*256+tid; row=t2>>2, col8=(t2&3)*8
    const int srow = tid >> 2;
    const int scol = (tid & 3) * 8;
    const unsigned short* Ag = A + (size_t)(row0 + srow) * K + scol;
    const unsigned short* Bg = B + (size_t)(col0 + srow) * K + scol;
    // wave-uniform LDS bases (elements): inst i, wave w -> i*2048 + w*512
    unsigned short* AsW = As + wid * 512;
    unsigned short* BsW = Bs + wid * 512;

    const unsigned short* AsR = As + (size_t)(wr * 64 + l16) * 32 + l4 * 8;
    const unsigned short* BsR = Bs + (size_t)(wc * 64 + l16) * 32 + l4 * 8;

    for (int k0 = 0; k0 < K; k0 += 32) {
        __syncthreads();   // previous iteration's frags consumed
        gld_lds16(AsW,        Ag + k0);                     // rows 0..63
        gld_lds16(AsW + 2048, Ag + (size_t)64 * K + k0);    // rows 64..127
        gld_lds16(BsW,        Bg + k0);
        gld_lds16(BsW + 2048, Bg + (size_t)64 * K + k0);
        __syncthreads();   // compiler drains vmcnt(0) before barrier

        bf16x8 af[4], bfr[4];
#pragma unroll
        for (int i = 0; i < 4; ++i)
            af[i] = *reinterpret_cast<const bf16x8*>(AsR + i * 16 * 32);
#pragma unroll
        for (int j = 0; j < 4; ++j)
            bfr[j] = *reinterpret_cast<const bf16x8*>(BsR + j * 16 * 32);
#pragma unroll
        for (int i = 0; i < 4; ++i)
#pragma unroll
            for (int j = 0; j < 4; ++j)
                acc[i][j] = __builtin_amdgcn_mfma_f32_16x16x32_bf16(
                    af[i], bfr[j], acc[i][j], 0, 0, 0);
    }

    // Epilogue. C/D frag layout (verified): col = lane&15, row = (lane>>4)*4+reg
    const int wrow0 = row0 + wr * 64;
    const int wcol0 = col0 + wc * 64;
#pragma unroll
    for (int j = 0; j < 4; ++j) {
        const int col = wcol0 + j * 16 + l16;
        const float bv = bias[col];
#pragma unroll
        for (int i = 0; i < 4; ++i) {
#pragma unroll
            for (int r = 0; r < 4; ++r) {
                const int row = wrow0 + i * 16 + l4 * 4 + r;
                const float v = acc[i][j][r] + bv;
                if (MODE == OUT_BF16) {
                    ((unsigned short*)Cout)[(size_t)row * N + col] = f32_to_bf16(v);
                } else if (MODE == OUT_F32) {
                    ((float*)Cout)[(size_t)row * N + col] = v;
                } else {  // OUT_VT: row=(b,s), col=(h,d) -> Vt[((b*NH+h)*HD+d)*SEQ+s]
                    const int b = row >> 11, s = row & (SEQ - 1);
                    const int h = col >> 7,  d = col & (HD_ - 1);
                    ((unsigned short*)Cout)[((size_t)((b * NH_ + h) * HD_ + d)) * SEQ + s] =
                        f32_to_bf16(v);
                }
            }
        }
    }
}

// ---------------------------------------------------------------------------
// Causal flash attention, v2.
// Q,K: (B*S, HID) bf16 row-major, head h at cols [h*128, h*128+128).
// Vt:  (B*NH*HD, S) bf16 row-major (s contiguous).
// O:   (B*S, HID) bf16 row-major.
// Grid: (64 q-subtiles of 32, B*NH) = 2048 blocks; block 128 = 2 waves;
// wave w owns q rows [qsub*32 + w*16, +16). Waves fully independent.
// LPT: qsub = 63 - blockIdx.x (heaviest blocks dispatched first).
// V ks=0 half prefetched before softmax to hide load latency.
// ---------------------------------------------------------------------------
__global__ __launch_bounds__(128)
void attn_fwd(const unsigned short* __restrict__ Qm,
              const unsigned short* __restrict__ Km,
              const unsigned short* __restrict__ Vt,
              unsigned short* __restrict__ Om) {
    const int tid  = threadIdx.x;
    const int lane = tid & 63;
    const int wq   = tid >> 6;          // 0..1
    const int l16  = lane & 15;
    const int l4   = lane >> 4;

    const int qsub = (int)gridDim.x - 1 - (int)blockIdx.x;  // heavy-first
    const int bh   = blockIdx.y;        // b*NH + h
    const int b    = bh >> 4;
    const int h    = bh & (NH_ - 1);

    const int qbase = qsub * 32 + wq * 16;

    __shared__ unsigned short plds[2][16][64];   // per-wave private P tile

    // Q fragments: rows qbase+l16, d-block kb*32 + l4*8
    const unsigned short* Qbase =
        Qm + ((size_t)(b * SEQ + qbase + l16)) * HID_ + h * HD_ + l4 * 8;
    bf16x8 qf[4];
#pragma unroll
    for (int kb = 0; kb < 4; ++kb)
        qf[kb] = *reinterpret_cast<const bf16x8*>(Qbase + kb * 32);

    float mrow[4], lrow[4];
#pragma unroll
    for (int r = 0; r < 4; ++r) { mrow[r] = -__builtin_inff(); lrow[r] = 0.f; }
    f32x4 acc[8] = {};

    const float scale = 0.08838834764831845f;  // 1/sqrt(128)
    const int qmax   = qbase + 15;
    const int ntiles = qmax / 64 + 1;

    const unsigned short* Kbh = Km + ((size_t)b * SEQ) * HID_ + h * HD_;
    const unsigned short* Vbh = Vt + (size_t)bh * HD_ * SEQ;

    for (int t = 0; t < ntiles; ++t) {
        const int kv0 = t * 64;

        // ---- scores: S[16 q][64 kv]  (4 column tiles) ----
        f32x4 sc[4];
#pragma unroll
        for (int ct = 0; ct < 4; ++ct) {
            f32x4 c = {};
            const unsigned short* Kp =
                Kbh + (size_t)(kv0 + ct * 16 + l16) * HID_ + l4 * 8;
#pragma unroll
            for (int kb = 0; kb < 4; ++kb) {
                bf16x8 kf = *reinterpret_cast<const bf16x8*>(Kp + kb * 32);
                c = __builtin_amdgcn_mfma_f32_16x16x32_bf16(qf[kb], kf, c, 0, 0, 0);
            }
            sc[ct] = c;
        }

        // ---- prefetch V (ks=0 half) so loads fly during softmax ----
        bf16x8 vf0[8];
#pragma unroll
        for (int dt = 0; dt < 8; ++dt)
            vf0[dt] = *reinterpret_cast<const bf16x8*>(
                Vbh + (size_t)(dt * 16 + l16) * SEQ + kv0 + l4 * 8);

        // ---- scale + causal mask (mask only on the diagonal tile) ----
        const bool needmask = (kv0 + 63 > qbase);
        if (needmask) {
#pragma unroll
            for (int ct = 0; ct < 4; ++ct) {
                const int col = kv0 + ct * 16 + l16;
#pragma unroll
                for (int r = 0; r < 4; ++r) {
                    float v = sc[ct][r] * scale;
                    const int qrow = qbase + l4 * 4 + r;
                    if (col > qrow) v = -__builtin_inff();
                    sc[ct][r] = v;
                }
            }
        } else {
#pragma unroll
            for (int ct = 0; ct < 4; ++ct)
#pragma unroll
                for (int r = 0; r < 4; ++r)
                    sc[ct][r] *= scale;
        }

        // ---- online softmax (row stats across 16-lane group) ----
        float tmax[4];
#pragma unroll
        for (int r = 0; r < 4; ++r) {
            float v = fmaxf(fmaxf(sc[0][r], sc[1][r]), fmaxf(sc[2][r], sc[3][r]));
#pragma unroll
            for (int off = 8; off >= 1; off >>= 1)
                v = fmaxf(v, __shfl_xor(v, off, 64));
            tmax[r] = v;
        }

        float alpha[4], rs[4];
#pragma unroll
        for (int r = 0; r < 4; ++r) {
            const float mn = fmaxf(mrow[r], tmax[r]);
            alpha[r] = __expf(mrow[r] - mn);   // expf(-inf)=0 on first tile
            mrow[r] = mn;
            rs[r] = 0.f;
        }

#pragma unroll
        for (int ct = 0; ct < 4; ++ct) {
#pragma unroll
            for (int r = 0; r < 4; ++r) {
                const float p = __expf(sc[ct][r] - mrow[r]);  // masked -> 0
                rs[r] += p;
                plds[wq][l4 * 4 + r][ct * 16 + l16] = f32_to_bf16(p);
            }
        }

#pragma unroll
        for (int r = 0; r < 4; ++r) {
#pragma unroll
            for (int off = 8; off >= 1; off >>= 1)
                rs[r] += __shfl_xor(rs[r], off, 64);
            lrow[r] = lrow[r] * alpha[r] + rs[r];
        }

        // ---- rescale O accumulator ----
#pragma unroll
        for (int dt = 0; dt < 8; ++dt)
#pragma unroll
            for (int r = 0; r < 4; ++r)
                acc[dt][r] *= alpha[r];

        // ---- PV: O += P[16x64] * V[64x128] ----
        asm volatile("s_waitcnt lgkmcnt(0)" ::: "memory");
        bf16x8 pf[2];
#pragma unroll
        for (int ks = 0; ks < 2; ++ks)
            pf[ks] = *reinterpret_cast<const bf16x8*>(&plds[wq][l16][ks * 32 + l4 * 8]);
#pragma unroll
        for (int dt = 0; dt < 8; ++dt) {
            acc[dt] = __builtin_amdgcn_mfma_f32_16x16x32_bf16(pf[0], vf0[dt], acc[dt], 0, 0, 0);
            bf16x8 vf1 = *reinterpret_cast<const bf16x8*>(
                Vbh + (size_t)(dt * 16 + l16) * SEQ + kv0 + 32 + l4 * 8);
            acc[dt] = __builtin_amdgcn_mfma_f32_16x16x32_bf16(pf[1], vf1, acc[dt], 0, 0, 0);
        }
    }

    // ---- epilogue: O row-major bf16 at (b, q, h*128 + d) ----
    unsigned short* Ob = Om + ((size_t)(b * SEQ + qbase)) * HID_ + h * HD_;
#pragma unroll
    for (int dt = 0; dt < 8; ++dt) {
#pragma unroll
        for (int r = 0; r < 4; ++r) {
            const int qrow = l4 * 4 + r;
            const float v = acc[dt][r] / lrow[r];
            Ob[(size_t)qrow * HID_ + dt * 16 + l16] = f32_to_bf16(v);
        }
    }
}

// ---------------------------------------------------------------------------
extern "C" void kernel_launch(void* const* d_in, const int* in_sizes, int n_in,
                              void* d_out, int out_size, void* d_ws, size_t ws_size,
                              hipStream_t stream) {
    const float* X  = (const float*)d_in[0];
    const float* Wq = (const float*)d_in[1];
    const float* bq = (const float*)d_in[2];
    const float* Wk = (const float*)d_in[3];
    const float* bk = (const float*)d_in[4];
    const float* Wv = (const float*)d_in[5];
    const float* bv = (const float*)d_in[6];
    const float* Wo = (const float*)d_in[7];
    const float* bo = (const float*)d_in[8];
    float* out = (float*)d_out;

    const size_t MK = (size_t)BATCH * SEQ * HID_;   // 8388608
    const size_t WK = (size_t)HID_ * HID_;          // 4194304

    unsigned short* ws  = (unsigned short*)d_ws;
    unsigned short* Xb  = ws;
    unsigned short* Wqb = Xb  + MK;
    unsigned short* Wkb = Wqb + WK;
    unsigned short* Wvb = Wkb + WK;
    unsigned short* Wob = Wvb + WK;
    unsigned short* Qb  = Wob + WK;
    unsigned short* Kb  = Qb  + MK;
    unsigned short* Vtb = Kb  + MK;
    unsigned short* AOb = Vtb + MK;

    auto cvt = [&](const float* src, unsigned short* dst, size_t n) {
        int n4 = (int)(n / 4);
        cvt_f32_bf16<<<(n4 + 255) / 256, 256, 0, stream>>>(src, dst, n4);
    };
    cvt(X,  Xb,  MK);
    cvt(Wq, Wqb, WK);
    cvt(Wk, Wkb, WK);
    cvt(Wv, Wvb, WK);
    cvt(Wo, Wob, WK);

    const int M = BATCH * SEQ;   // 4096
    dim3 g(HID_ / 128, M / 128); // (16, 32)

    gemm_bt<OUT_BF16><<<g, 256, 0, stream>>>(Xb, Wqb, bq, Qb,  M, HID_, HID_);
    gemm_bt<OUT_BF16><<<g, 256, 0, stream>>>(Xb, Wkb, bk, Kb,  M, HID_, HID_);
    gemm_bt<OUT_VT>  <<<g, 256, 0, stream>>>(Xb, Wvb, bv, Vtb, M, HID_, HID_);

    attn_fwd<<<dim3(64, BATCH * NH_), 128, 0, stream>>>(Qb, Kb, Vtb, AOb);

    gemm_bt<OUT_F32><<<g, 256, 0, stream>>>(AOb, Wob, bo, out, M, HID_, HID_);
}

// Round 4
// 705.156 us; speedup vs baseline: 1.6220x; 1.1035x over previous
//
#include <hip/hip_runtime.h>
#include <hip/hip_bf16.h>

// Problem constants
#define BATCH 2
#define SEQ   2048
#define HID_  2048
#define NH_   16
#define HD_   128

typedef __bf16 bf16x8 __attribute__((ext_vector_type(8)));
typedef float  f32x4  __attribute__((ext_vector_type(4)));

__device__ __forceinline__ unsigned short f32_to_bf16(float f) {
    unsigned int u = __builtin_bit_cast(unsigned int, f);
    unsigned int r = (u + 0x7fffu + ((u >> 16) & 1u)) >> 16;
    return (unsigned short)r;
}

// async global->LDS, 16 bytes per lane. lds must be the WAVE-UNIFORM base;
// HW writes lane i at lds + i*16. g is the per-lane global source.
__device__ __forceinline__ void gld_lds16(void* lds, const void* g) {
    __builtin_amdgcn_global_load_lds(
        (const __attribute__((address_space(1))) unsigned int*)g,
        (__attribute__((address_space(3))) unsigned int*)lds, 16, 0, 0);
}

// ---------------------------------------------------------------------------
// fp32 -> bf16 conversion, 4 elements / thread
// ---------------------------------------------------------------------------
__global__ void cvt_f32_bf16(const float* __restrict__ in,
                             unsigned short* __restrict__ out, int n4) {
    int i = blockIdx.x * blockDim.x + threadIdx.x;
    if (i >= n4) return;
    float4 a = reinterpret_cast<const float4*>(in)[i];
    ushort4 o;
    o.x = f32_to_bf16(a.x);
    o.y = f32_to_bf16(a.y);
    o.z = f32_to_bf16(a.z);
    o.w = f32_to_bf16(a.w);
    reinterpret_cast<ushort4*>(out)[i] = o;
}

// ---------------------------------------------------------------------------
// GEMM: C[M,N] = A[M,K] * B[N,K]^T + bias[N]  (m97 structure: 128x128 tile,
// BK=32, LDS staged via global_load_lds width 16, 2 barriers / K-step).
// ---------------------------------------------------------------------------
enum { OUT_BF16 = 0, OUT_VT = 1, OUT_F32 = 2 };

template <int MODE>
__global__ __launch_bounds__(256)
void gemm_bt(const unsigned short* __restrict__ A,
             const unsigned short* __restrict__ B,
             const float* __restrict__ bias,
             void* __restrict__ Cout,
             int M, int N, int K) {
    const int tid  = threadIdx.x;
    const int lane = tid & 63;
    const int wid  = tid >> 6;          // 0..3
    const int wr   = wid >> 1;          // 0..1
    const int wc   = wid & 1;           // 0..1
    const int l16  = lane & 15;
    const int l4   = lane >> 4;         // 0..3

    const int row0 = blockIdx.y * 128;  // block A rows
    const int col0 = blockIdx.x * 128;  // block B rows (C cols)

    __shared__ unsigned short As[128 * 32];
    __shared__ unsigned short Bs[128 * 32];

    f32x4 acc[4][4] = {};

    const int srow = tid >> 2;
    const int scol = (tid & 3) * 8;
    const unsigned short* Ag = A + (size_t)(row0 + srow) * K + scol;
    const unsigned short* Bg = B + (size_t)(col0 + srow) * K + scol;
    unsigned short* AsW = As + wid * 512;
    unsigned short* BsW = Bs + wid * 512;

    const unsigned short* AsR = As + (size_t)(wr * 64 + l16) * 32 + l4 * 8;
    const unsigned short* BsR = Bs + (size_t)(wc * 64 + l16) * 32 + l4 * 8;

    for (int k0 = 0; k0 < K; k0 += 32) {
        __syncthreads();
        gld_lds16(AsW,        Ag + k0);
        gld_lds16(AsW + 2048, Ag + (size_t)64 * K + k0);
        gld_lds16(BsW,        Bg + k0);
        gld_lds16(BsW + 2048, Bg + (size_t)64 * K + k0);
        __syncthreads();

        bf16x8 af[4], bfr[4];
#pragma unroll
        for (int i = 0; i < 4; ++i)
            af[i] = *reinterpret_cast<const bf16x8*>(AsR + i * 16 * 32);
#pragma unroll
        for (int j = 0; j < 4; ++j)
            bfr[j] = *reinterpret_cast<const bf16x8*>(BsR + j * 16 * 32);
#pragma unroll
        for (int i = 0; i < 4; ++i)
#pragma unroll
            for (int j = 0; j < 4; ++j)
                acc[i][j] = __builtin_amdgcn_mfma_f32_16x16x32_bf16(
                    af[i], bfr[j], acc[i][j], 0, 0, 0);
    }

    const int wrow0 = row0 + wr * 64;
    const int wcol0 = col0 + wc * 64;
#pragma unroll
    for (int j = 0; j < 4; ++j) {
        const int col = wcol0 + j * 16 + l16;
        const float bv = bias[col];
#pragma unroll
        for (int i = 0; i < 4; ++i) {
#pragma unroll
            for (int r = 0; r < 4; ++r) {
                const int row = wrow0 + i * 16 + l4 * 4 + r;
                const float v = acc[i][j][r] + bv;
                if (MODE == OUT_BF16) {
                    ((unsigned short*)Cout)[(size_t)row * N + col] = f32_to_bf16(v);
                } else if (MODE == OUT_F32) {
                    ((float*)Cout)[(size_t)row * N + col] = v;
                } else {  // OUT_VT
                    const int b = row >> 11, s = row & (SEQ - 1);
                    const int h = col >> 7,  d = col & (HD_ - 1);
                    ((unsigned short*)Cout)[((size_t)((b * NH_ + h) * HD_ + d)) * SEQ + s] =
                        f32_to_bf16(v);
                }
            }
        }
    }
}

// ---------------------------------------------------------------------------
// Causal flash attention, v3: single-wave blocks, 16 q rows / wave,
// register-double-buffered K tiles (kfA/kfB), V ks=0 half prefetched.
// Q,K: (B*S, HID) bf16 row-major; Vt: (B*NH*HD, S) bf16; O: (B*S, HID) bf16.
// Grid: (128 q-subtiles, B*NH) = 4096 blocks of 64 thr. LPT heavy-first.
// ---------------------------------------------------------------------------
__global__ __launch_bounds__(64, 2)
void attn_fwd(const unsigned short* __restrict__ Qm,
              const unsigned short* __restrict__ Km,
              const unsigned short* __restrict__ Vt,
              unsigned short* __restrict__ Om) {
    const int lane = threadIdx.x & 63;
    const int l16  = lane & 15;
    const int l4   = lane >> 4;

    const int qsub = (int)gridDim.x - 1 - (int)blockIdx.x;  // heavy-first
    const int bh   = blockIdx.y;        // b*NH + h
    const int b    = bh >> 4;
    const int h    = bh & (NH_ - 1);

    const int qbase = qsub * 16;

    __shared__ unsigned short plds[16][68];   // +4 pad: conflict-free transpose

    const unsigned short* Qbase =
        Qm + ((size_t)(b * SEQ + qbase + l16)) * HID_ + h * HD_ + l4 * 8;
    bf16x8 qf[4];
#pragma unroll
    for (int kb = 0; kb < 4; ++kb)
        qf[kb] = *reinterpret_cast<const bf16x8*>(Qbase + kb * 32);

    float mrow[4], lrow[4];
#pragma unroll
    for (int r = 0; r < 4; ++r) { mrow[r] = -__builtin_inff(); lrow[r] = 0.f; }
    f32x4 acc[8] = {};

    const float scale = 0.08838834764831845f;  // 1/sqrt(128)
    const int ntiles = (qbase + 15) / 64 + 1;

    const unsigned short* Kbh = Km + ((size_t)b * SEQ) * HID_ + h * HD_;
    const unsigned short* Vbh = Vt + (size_t)bh * HD_ * SEQ;

    bf16x8 kfA[16], kfB[16];
    // preload K tile 0
#pragma unroll
    for (int ct = 0; ct < 4; ++ct)
#pragma unroll
        for (int kb = 0; kb < 4; ++kb)
            kfA[ct * 4 + kb] = *reinterpret_cast<const bf16x8*>(
                Kbh + (size_t)(ct * 16 + l16) * HID_ + kb * 32 + l4 * 8);

    auto tile = [&](bf16x8* kc, bf16x8* kn, int t) {
        const int kv0 = t * 64;
        // ---- issue next-tile K loads (clamped; values unused on last tile) ----
        const int kvn = ((t + 1) * 64 > SEQ - 64) ? (SEQ - 64) : (t + 1) * 64;
#pragma unroll
        for (int ct = 0; ct < 4; ++ct)
#pragma unroll
            for (int kb = 0; kb < 4; ++kb)
                kn[ct * 4 + kb] = *reinterpret_cast<const bf16x8*>(
                    Kbh + (size_t)(kvn + ct * 16 + l16) * HID_ + kb * 32 + l4 * 8);
        // ---- issue V (ks=0 half) loads ----
        bf16x8 vf0[8];
#pragma unroll
        for (int dt = 0; dt < 8; ++dt)
            vf0[dt] = *reinterpret_cast<const bf16x8*>(
                Vbh + (size_t)(dt * 16 + l16) * SEQ + kv0 + l4 * 8);

        // ---- QK^T from registers (no memory wait) ----
        f32x4 sc[4];
#pragma unroll
        for (int ct = 0; ct < 4; ++ct) {
            f32x4 c = {};
#pragma unroll
            for (int kb = 0; kb < 4; ++kb)
                c = __builtin_amdgcn_mfma_f32_16x16x32_bf16(qf[kb], kc[ct * 4 + kb], c, 0, 0, 0);
            sc[ct] = c;
        }

        // ---- scale + causal mask (only the diagonal tile: t == ntiles-1) ----
        if (t == ntiles - 1) {
#pragma unroll
            for (int ct = 0; ct < 4; ++ct) {
                const int col = kv0 + ct * 16 + l16;
#pragma unroll
                for (int r = 0; r < 4; ++r) {
                    float v = sc[ct][r] * scale;
                    const int qrow = qbase + l4 * 4 + r;
                    if (col > qrow) v = -__builtin_inff();
                    sc[ct][r] = v;
                }
            }
        } else {
#pragma unroll
            for (int ct = 0; ct < 4; ++ct)
#pragma unroll
                for (int r = 0; r < 4; ++r)
                    sc[ct][r] *= scale;
        }

        // ---- online softmax (row stats across 16-lane group) ----
        float tmax[4];
#pragma unroll
        for (int r = 0; r < 4; ++r) {
            float v = fmaxf(fmaxf(sc[0][r], sc[1][r]), fmaxf(sc[2][r], sc[3][r]));
#pragma unroll
            for (int off = 8; off >= 1; off >>= 1)
                v = fmaxf(v, __shfl_xor(v, off, 64));
            tmax[r] = v;
        }

        float alpha[4], rs[4];
#pragma unroll
        for (int r = 0; r < 4; ++r) {
            const float mn = fmaxf(mrow[r], tmax[r]);
            alpha[r] = __expf(mrow[r] - mn);
            mrow[r] = mn;
            rs[r] = 0.f;
        }

#pragma unroll
        for (int ct = 0; ct < 4; ++ct) {
#pragma unroll
            for (int r = 0; r < 4; ++r) {
                const float p = __expf(sc[ct][r] - mrow[r]);
                rs[r] += p;
                plds[l4 * 4 + r][ct * 16 + l16] = f32_to_bf16(p);
            }
        }

#pragma unroll
        for (int r = 0; r < 4; ++r) {
#pragma unroll
            for (int off = 8; off >= 1; off >>= 1)
                rs[r] += __shfl_xor(rs[r], off, 64);
            lrow[r] = lrow[r] * alpha[r] + rs[r];
        }

        // ---- rescale O accumulator ----
#pragma unroll
        for (int dt = 0; dt < 8; ++dt)
#pragma unroll
            for (int r = 0; r < 4; ++r)
                acc[dt][r] *= alpha[r];

        // ---- PV: O += P[16x64] * V[64x128] ----
        asm volatile("s_waitcnt lgkmcnt(0)" ::: "memory");
        bf16x8 pf[2];
#pragma unroll
        for (int ks = 0; ks < 2; ++ks)
            pf[ks] = *reinterpret_cast<const bf16x8*>(&plds[l16][ks * 32 + l4 * 8]);
#pragma unroll
        for (int dt = 0; dt < 8; ++dt) {
            acc[dt] = __builtin_amdgcn_mfma_f32_16x16x32_bf16(pf[0], vf0[dt], acc[dt], 0, 0, 0);
            bf16x8 vf1 = *reinterpret_cast<const bf16x8*>(
                Vbh + (size_t)(dt * 16 + l16) * SEQ + kv0 + 32 + l4 * 8);
            acc[dt] = __builtin_amdgcn_mfma_f32_16x16x32_bf16(pf[1], vf1, acc[dt], 0, 0, 0);
        }
    };

    int t = 0;
    for (;;) {
        tile(kfA, kfB, t); ++t; if (t == ntiles) break;
        tile(kfB, kfA, t); ++t; if (t == ntiles) break;
    }

    // ---- epilogue: O row-major bf16 at (b, q, h*128 + d) ----
    unsigned short* Ob = Om + ((size_t)(b * SEQ + qbase)) * HID_ + h * HD_;
#pragma unroll
    for (int dt = 0; dt < 8; ++dt) {
#pragma unroll
        for (int r = 0; r < 4; ++r) {
            const int qrow = l4 * 4 + r;
            const float v = acc[dt][r] / lrow[r];
            Ob[(size_t)qrow * HID_ + dt * 16 + l16] = f32_to_bf16(v);
        }
    }
}

// ---------------------------------------------------------------------------
extern "C" void kernel_launch(void* const* d_in, const int* in_sizes, int n_in,
                              void* d_out, int out_size, void* d_ws, size_t ws_size,
                              hipStream_t stream) {
    const float* X  = (const float*)d_in[0];
    const float* Wq = (const float*)d_in[1];
    const float* bq = (const float*)d_in[2];
    const float* Wk = (const float*)d_in[3];
    const float* bk = (const float*)d_in[4];
    const float* Wv = (const float*)d_in[5];
    const float* bv = (const float*)d_in[6];
    const float* Wo = (const float*)d_in[7];
    const float* bo = (const float*)d_in[8];
    float* out = (float*)d_out;

    const size_t MK = (size_t)BATCH * SEQ * HID_;   // 8388608
    const size_t WK = (size_t)HID_ * HID_;          // 4194304

    unsigned short* ws  = (unsigned short*)d_ws;
    unsigned short* Xb  = ws;
    unsigned short* Wqb = Xb  + MK;
    unsigned short* Wkb = Wqb + WK;
    unsigned short* Wvb = Wkb + WK;
    unsigned short* Wob = Wvb + WK;
    unsigned short* Qb  = Wob + WK;
    unsigned short* Kb  = Qb  + MK;
    unsigned short* Vtb = Kb  + MK;
    unsigned short* AOb = Vtb + MK;

    auto cvt = [&](const float* src, unsigned short* dst, size_t n) {
        int n4 = (int)(n / 4);
        cvt_f32_bf16<<<(n4 + 255) / 256, 256, 0, stream>>>(src, dst, n4);
    };
    cvt(X,  Xb,  MK);
    cvt(Wq, Wqb, WK);
    cvt(Wk, Wkb, WK);
    cvt(Wv, Wvb, WK);
    cvt(Wo, Wob, WK);

    const int M = BATCH * SEQ;   // 4096
    dim3 g(HID_ / 128, M / 128); // (16, 32)

    gemm_bt<OUT_BF16><<<g, 256, 0, stream>>>(Xb, Wqb, bq, Qb,  M, HID_, HID_);
    gemm_bt<OUT_BF16><<<g, 256, 0, stream>>>(Xb, Wkb, bk, Kb,  M, HID_, HID_);
    gemm_bt<OUT_VT>  <<<g, 256, 0, stream>>>(Xb, Wvb, bv, Vtb, M, HID_, HID_);

    attn_fwd<<<dim3(128, BATCH * NH_), 64, 0, stream>>>(Qb, Kb, Vtb, AOb);

    gemm_bt<OUT_F32><<<g, 256, 0, stream>>>(AOb, Wob, bo, out, M, HID_, HID_);
}

// Round 5
// 455.418 us; speedup vs baseline: 2.5114x; 1.5484x over previous
//
#include <hip/hip_runtime.h>
#include <hip/hip_bf16.h>

// Problem constants
#define BATCH 2
#define SEQ   2048
#define HID_  2048
#define NH_   16
#define HD_   128

typedef __bf16 bf16x8 __attribute__((ext_vector_type(8)));
typedef float  f32x4  __attribute__((ext_vector_type(4)));

__device__ __forceinline__ unsigned short f32_to_bf16(float f) {
    unsigned int u = __builtin_bit_cast(unsigned int, f);
    unsigned int r = (u + 0x7fffu + ((u >> 16) & 1u)) >> 16;
    return (unsigned short)r;
}

// async global->LDS, 16 bytes per lane. lds must be the WAVE-UNIFORM base;
// HW writes lane i at lds + i*16. g is the per-lane global source.
__device__ __forceinline__ void gld_lds16(void* lds, const void* g) {
    __builtin_amdgcn_global_load_lds(
        (const __attribute__((address_space(1))) unsigned int*)g,
        (__attribute__((address_space(3))) unsigned int*)lds, 16, 0, 0);
}

// ---------------------------------------------------------------------------
// fp32 -> bf16 conversion, 4 elements / thread
// ---------------------------------------------------------------------------
__global__ void cvt_f32_bf16(const float* __restrict__ in,
                             unsigned short* __restrict__ out, int n4) {
    int i = blockIdx.x * blockDim.x + threadIdx.x;
    if (i >= n4) return;
    float4 a = reinterpret_cast<const float4*>(in)[i];
    ushort4 o;
    o.x = f32_to_bf16(a.x);
    o.y = f32_to_bf16(a.y);
    o.z = f32_to_bf16(a.z);
    o.w = f32_to_bf16(a.w);
    reinterpret_cast<ushort4*>(out)[i] = o;
}

// ---------------------------------------------------------------------------
// GEMM: C[M,N] = A[M,K] * B[N,K]^T + bias[N]  (m97 structure: 128x128 tile,
// BK=32, LDS staged via global_load_lds width 16, 2 barriers / K-step).
// ---------------------------------------------------------------------------
enum { OUT_BF16 = 0, OUT_VT = 1, OUT_F32 = 2 };

template <int MODE>
__global__ __launch_bounds__(256)
void gemm_bt(const unsigned short* __restrict__ A,
             const unsigned short* __restrict__ B,
             const float* __restrict__ bias,
             void* __restrict__ Cout,
             int M, int N, int K) {
    const int tid  = threadIdx.x;
    const int lane = tid & 63;
    const int wid  = tid >> 6;          // 0..3
    const int wr   = wid >> 1;          // 0..1
    const int wc   = wid & 1;           // 0..1
    const int l16  = lane & 15;
    const int l4   = lane >> 4;         // 0..3

    const int row0 = blockIdx.y * 128;  // block A rows
    const int col0 = blockIdx.x * 128;  // block B rows (C cols)

    __shared__ unsigned short As[128 * 32];
    __shared__ unsigned short Bs[128 * 32];

    f32x4 acc[4][4] = {};

    const int srow = tid >> 2;
    const int scol = (tid & 3) * 8;
    const unsigned short* Ag = A + (size_t)(row0 + srow) * K + scol;
    const unsigned short* Bg = B + (size_t)(col0 + srow) * K + scol;
    unsigned short* AsW = As + wid * 512;
    unsigned short* BsW = Bs + wid * 512;

    const unsigned short* AsR = As + (size_t)(wr * 64 + l16) * 32 + l4 * 8;
    const unsigned short* BsR = Bs + (size_t)(wc * 64 + l16) * 32 + l4 * 8;

    for (int k0 = 0; k0 < K; k0 += 32) {
        __syncthreads();
        gld_lds16(AsW,        Ag + k0);
        gld_lds16(AsW + 2048, Ag + (size_t)64 * K + k0);
        gld_lds16(BsW,        Bg + k0);
        gld_lds16(BsW + 2048, Bg + (size_t)64 * K + k0);
        __syncthreads();

        bf16x8 af[4], bfr[4];
#pragma unroll
        for (int i = 0; i < 4; ++i)
            af[i] = *reinterpret_cast<const bf16x8*>(AsR + i * 16 * 32);
#pragma unroll
        for (int j = 0; j < 4; ++j)
            bfr[j] = *reinterpret_cast<const bf16x8*>(BsR + j * 16 * 32);
#pragma unroll
        for (int i = 0; i < 4; ++i)
#pragma unroll
            for (int j = 0; j < 4; ++j)
                acc[i][j] = __builtin_amdgcn_mfma_f32_16x16x32_bf16(
                    af[i], bfr[j], acc[i][j], 0, 0, 0);
    }

    const int wrow0 = row0 + wr * 64;
    const int wcol0 = col0 + wc * 64;
#pragma unroll
    for (int j = 0; j < 4; ++j) {
        const int col = wcol0 + j * 16 + l16;
        const float bv = bias[col];
#pragma unroll
        for (int i = 0; i < 4; ++i) {
#pragma unroll
            for (int r = 0; r < 4; ++r) {
                const int row = wrow0 + i * 16 + l4 * 4 + r;
                const float v = acc[i][j][r] + bv;
                if (MODE == OUT_BF16) {
                    ((unsigned short*)Cout)[(size_t)row * N + col] = f32_to_bf16(v);
                } else if (MODE == OUT_F32) {
                    ((float*)Cout)[(size_t)row * N + col] = v;
                } else {  // OUT_VT
                    const int b = row >> 11, s = row & (SEQ - 1);
                    const int h = col >> 7,  d = col & (HD_ - 1);
                    ((unsigned short*)Cout)[((size_t)((b * NH_ + h) * HD_ + d)) * SEQ + s] =
                        f32_to_bf16(v);
                }
            }
        }
    }
}

// ---------------------------------------------------------------------------
// Causal flash attention, v4: cooperative 4-wave blocks, 64 q rows / block
// (16 per wave). K (64x128) and V^T (128x64) tiles staged once per block in
// double-buffered LDS via global_load_lds, XOR-swizzled both sides (T2 +
// rule #21: linear LDS dest, inverse-swizzled global src, swizzled ds_read).
// Grid: (B*NH, SEQ/64), qt = 31 - blockIdx.y (global heavy-first LPT);
// same-bh blocks are 32 apart in dispatch order -> same XCD (L2 locality).
// ---------------------------------------------------------------------------
__global__ __launch_bounds__(256, 2)
void attn_fwd(const unsigned short* __restrict__ Qm,
              const unsigned short* __restrict__ Km,
              const unsigned short* __restrict__ Vt,
              unsigned short* __restrict__ Om) {
    const int tid  = threadIdx.x;
    const int lane = tid & 63;
    const int wq   = tid >> 6;          // wave 0..3
    const int l16  = lane & 15;
    const int l4   = lane >> 4;

    const int bh = blockIdx.x;          // b*NH + h
    const int qt = (int)gridDim.y - 1 - (int)blockIdx.y;  // heavy-first
    const int b  = bh >> 4;
    const int h  = bh & (NH_ - 1);

    const int qbase  = qt * 64 + wq * 16;
    const int ntiles = qt + 1;

    __shared__ unsigned short Ks[2][64 * 128];   // [kv][d], swizzled chunks
    __shared__ unsigned short Vs[2][128 * 64];   // [d][kv], swizzled chunks
    __shared__ unsigned short plds[4][16][68];   // per-wave P transpose

    const unsigned short* Kbh = Km + ((size_t)b * SEQ) * HID_ + h * HD_;
    const unsigned short* Vbh = Vt + (size_t)bh * HD_ * SEQ;

    // ---- stage tile t into buffer buf (each wave does its 1/4 share) ----
    auto stage = [&](int buf, int t) {
        const int kv0 = t * 64;
        {   // K: wave wq covers rows 16wq..16wq+15 (4 instrs x 4 rows)
            const int rl = lane >> 4;        // 0..3
            const int ck = lane & 15;        // physical 16B chunk
#pragma unroll
            for (int j = 0; j < 4; ++j) {
                const int r  = wq * 16 + 4 * j + rl;
                const int lc = ck ^ (r & 7); // logical chunk (involution)
                gld_lds16(&Ks[buf][(wq * 16 + 4 * j) * 128],
                          Kbh + (size_t)(kv0 + r) * HID_ + lc * 8);
            }
        }
        {   // V^T: wave wq covers rows 32wq..32wq+31 (4 instrs x 8 rows)
            const int rl = lane >> 3;        // 0..7
            const int ck = lane & 7;
#pragma unroll
            for (int j = 0; j < 4; ++j) {
                const int r  = wq * 32 + 8 * j + rl;
                const int lc = ck ^ (r & 7);
                gld_lds16(&Vs[buf][(wq * 32 + 8 * j) * 64],
                          Vbh + (size_t)r * SEQ + kv0 + lc * 8);
            }
        }
    };

    // ---- Q fragments (register-resident) ----
    stage(0, 0);
    const unsigned short* Qbase =
        Qm + ((size_t)(b * SEQ + qbase + l16)) * HID_ + h * HD_ + l4 * 8;
    bf16x8 qf[4];
#pragma unroll
    for (int kb = 0; kb < 4; ++kb)
        qf[kb] = *reinterpret_cast<const bf16x8*>(Qbase + kb * 32);

    float mrow[4], lrow[4];
#pragma unroll
    for (int r = 0; r < 4; ++r) { mrow[r] = -__builtin_inff(); lrow[r] = 0.f; }
    f32x4 acc[8] = {};

    const float scale = 0.08838834764831845f;  // 1/sqrt(128)

    int buf = 0;
    for (int t = 0; t < ntiles; ++t) {
        __syncthreads();                     // tile t staged & visible
        if (t + 1 < ntiles) stage(buf ^ 1, t + 1);

        const unsigned short* Kb0 = &Ks[buf][0];
        const unsigned short* Vb0 = &Vs[buf][0];
        const int kv0 = t * 64;
        const int sw  = l16 & 7;             // read-side swizzle key

        // ---- QK^T: S[16 q][64 kv] ----
        f32x4 sc[4];
#pragma unroll
        for (int ct = 0; ct < 4; ++ct) {
            f32x4 c = {};
#pragma unroll
            for (int kb = 0; kb < 4; ++kb) {
                bf16x8 kf = *reinterpret_cast<const bf16x8*>(
                    Kb0 + (ct * 16 + l16) * 128 + ((kb * 4 + l4) ^ sw) * 8);
                c = __builtin_amdgcn_mfma_f32_16x16x32_bf16(qf[kb], kf, c, 0, 0, 0);
            }
            sc[ct] = c;
        }

        // ---- scale + causal mask (diagonal tile only) ----
        if (t == ntiles - 1) {
#pragma unroll
            for (int ct = 0; ct < 4; ++ct) {
                const int col = kv0 + ct * 16 + l16;
#pragma unroll
                for (int r = 0; r < 4; ++r) {
                    float v = sc[ct][r] * scale;
                    const int qrow = qbase + l4 * 4 + r;
                    if (col > qrow) v = -__builtin_inff();
                    sc[ct][r] = v;
                }
            }
        } else {
#pragma unroll
            for (int ct = 0; ct < 4; ++ct)
#pragma unroll
                for (int r = 0; r < 4; ++r)
                    sc[ct][r] *= scale;
        }

        // ---- online softmax (row stats across 16-lane group) ----
        float tmax[4];
#pragma unroll
        for (int r = 0; r < 4; ++r) {
            float v = fmaxf(fmaxf(sc[0][r], sc[1][r]), fmaxf(sc[2][r], sc[3][r]));
#pragma unroll
            for (int off = 8; off >= 1; off >>= 1)
                v = fmaxf(v, __shfl_xor(v, off, 64));
            tmax[r] = v;
        }

        float alpha[4], rs[4];
#pragma unroll
        for (int r = 0; r < 4; ++r) {
            const float mn = fmaxf(mrow[r], tmax[r]);
            alpha[r] = __expf(mrow[r] - mn);
            mrow[r] = mn;
            rs[r] = 0.f;
        }

#pragma unroll
        for (int ct = 0; ct < 4; ++ct) {
#pragma unroll
            for (int r = 0; r < 4; ++r) {
                const float p = __expf(sc[ct][r] - mrow[r]);
                rs[r] += p;
                plds[wq][l4 * 4 + r][ct * 16 + l16] = f32_to_bf16(p);
            }
        }

#pragma unroll
        for (int r = 0; r < 4; ++r) {
#pragma unroll
            for (int off = 8; off >= 1; off >>= 1)
                rs[r] += __shfl_xor(rs[r], off, 64);
            lrow[r] = lrow[r] * alpha[r] + rs[r];
        }

        // ---- rescale O accumulator ----
#pragma unroll
        for (int dt = 0; dt < 8; ++dt)
#pragma unroll
            for (int r = 0; r < 4; ++r)
                acc[dt][r] *= alpha[r];

        // ---- PV: O += P[16x64] * V[64x128] ----
        asm volatile("s_waitcnt lgkmcnt(0)" ::: "memory");
        bf16x8 pf[2];
#pragma unroll
        for (int ks = 0; ks < 2; ++ks)
            pf[ks] = *reinterpret_cast<const bf16x8*>(&plds[wq][l16][ks * 32 + l4 * 8]);
#pragma unroll
        for (int dt = 0; dt < 8; ++dt) {
#pragma unroll
            for (int ks = 0; ks < 2; ++ks) {
                bf16x8 vf = *reinterpret_cast<const bf16x8*>(
                    Vb0 + (dt * 16 + l16) * 64 + ((ks * 4 + l4) ^ sw) * 8);
                acc[dt] = __builtin_amdgcn_mfma_f32_16x16x32_bf16(pf[ks], vf, acc[dt], 0, 0, 0);
            }
        }

        buf ^= 1;
    }

    // ---- epilogue: O row-major bf16 at (b, q, h*128 + d) ----
    unsigned short* Ob = Om + ((size_t)(b * SEQ + qbase)) * HID_ + h * HD_;
#pragma unroll
    for (int dt = 0; dt < 8; ++dt) {
#pragma unroll
        for (int r = 0; r < 4; ++r) {
            const int qrow = l4 * 4 + r;
            const float v = acc[dt][r] / lrow[r];
            Ob[(size_t)qrow * HID_ + dt * 16 + l16] = f32_to_bf16(v);
        }
    }
}

// ---------------------------------------------------------------------------
extern "C" void kernel_launch(void* const* d_in, const int* in_sizes, int n_in,
                              void* d_out, int out_size, void* d_ws, size_t ws_size,
                              hipStream_t stream) {
    const float* X  = (const float*)d_in[0];
    const float* Wq = (const float*)d_in[1];
    const float* bq = (const float*)d_in[2];
    const float* Wk = (const float*)d_in[3];
    const float* bk = (const float*)d_in[4];
    const float* Wv = (const float*)d_in[5];
    const float* bv = (const float*)d_in[6];
    const float* Wo = (const float*)d_in[7];
    const float* bo = (const float*)d_in[8];
    float* out = (float*)d_out;

    const size_t MK = (size_t)BATCH * SEQ * HID_;   // 8388608
    const size_t WK = (size_t)HID_ * HID_;          // 4194304

    unsigned short* ws  = (unsigned short*)d_ws;
    unsigned short* Xb  = ws;
    unsigned short* Wqb = Xb  + MK;
    unsigned short* Wkb = Wqb + WK;
    unsigned short* Wvb = Wkb + WK;
    unsigned short* Wob = Wvb + WK;
    unsigned short* Qb  = Wob + WK;
    unsigned short* Kb  = Qb  + MK;
    unsigned short* Vtb = Kb  + MK;
    unsigned short* AOb = Vtb + MK;

    auto cvt = [&](const float* src, unsigned short* dst, size_t n) {
        int n4 = (int)(n / 4);
        cvt_f32_bf16<<<(n4 + 255) / 256, 256, 0, stream>>>(src, dst, n4);
    };
    cvt(X,  Xb,  MK);
    cvt(Wq, Wqb, WK);
    cvt(Wk, Wkb, WK);
    cvt(Wv, Wvb, WK);
    cvt(Wo, Wob, WK);

    const int M = BATCH * SEQ;   // 4096
    dim3 g(HID_ / 128, M / 128); // (16, 32)

    gemm_bt<OUT_BF16><<<g, 256, 0, stream>>>(Xb, Wqb, bq, Qb,  M, HID_, HID_);
    gemm_bt<OUT_BF16><<<g, 256, 0, stream>>>(Xb, Wkb, bk, Kb,  M, HID_, HID_);
    gemm_bt<OUT_VT>  <<<g, 256, 0, stream>>>(Xb, Wvb, bv, Vtb, M, HID_, HID_);

    attn_fwd<<<dim3(BATCH * NH_, SEQ / 64), 256, 0, stream>>>(Qb, Kb, Vtb, AOb);

    gemm_bt<OUT_F32><<<g, 256, 0, stream>>>(AOb, Wob, bo, out, M, HID_, HID_);
}

// Round 6
// 426.975 us; speedup vs baseline: 2.6787x; 1.0666x over previous
//
#include <hip/hip_runtime.h>
#include <hip/hip_bf16.h>

// Problem constants
#define BATCH 2
#define SEQ   2048
#define HID_  2048
#define NH_   16
#define HD_   128

typedef __bf16 bf16x8 __attribute__((ext_vector_type(8)));
typedef float  f32x4  __attribute__((ext_vector_type(4)));

__device__ __forceinline__ unsigned short f32_to_bf16(float f) {
    unsigned int u = __builtin_bit_cast(unsigned int, f);
    unsigned int r = (u + 0x7fffu + ((u >> 16) & 1u)) >> 16;
    return (unsigned short)r;
}

// async global->LDS, 16 bytes per lane. lds must be the WAVE-UNIFORM base;
// HW writes lane i at lds + i*16. g is the per-lane global source.
__device__ __forceinline__ void gld_lds16(void* lds, const void* g) {
    __builtin_amdgcn_global_load_lds(
        (const __attribute__((address_space(1))) unsigned int*)g,
        (__attribute__((address_space(3))) unsigned int*)lds, 16, 0, 0);
}

// ---------------------------------------------------------------------------
// fp32 -> bf16 conversion, 4 elements / thread
// ---------------------------------------------------------------------------
__global__ void cvt_f32_bf16(const float* __restrict__ in,
                             unsigned short* __restrict__ out, int n4) {
    int i = blockIdx.x * blockDim.x + threadIdx.x;
    if (i >= n4) return;
    float4 a = reinterpret_cast<const float4*>(in)[i];
    ushort4 o;
    o.x = f32_to_bf16(a.x);
    o.y = f32_to_bf16(a.y);
    o.z = f32_to_bf16(a.z);
    o.w = f32_to_bf16(a.w);
    reinterpret_cast<ushort4*>(out)[i] = o;
}

// ---------------------------------------------------------------------------
// Fused QKV GEMM: C[M, 6144] = X[M,K] * Wqkv[6144,K]^T + bias(seg)
// Wqkv = contiguous bf16 [Wq; Wk; Wv].  Epilogue per column segment
// (block-uniform, 2048 % 128 == 0):
//   seg 0 -> Q bf16 row-major, seg 1 -> K bf16 row-major,
//   seg 2 -> V^T bf16 (b,h,d,s).
// m97 structure: 128x128 tile, BK=32, global_load_lds w16, 2 barriers/step.
// Grid (48, 32) = 1536 blocks.
// ---------------------------------------------------------------------------
__global__ __launch_bounds__(256)
void gemm_qkv(const unsigned short* __restrict__ A,
              const unsigned short* __restrict__ B,
              const float* __restrict__ bq,
              const float* __restrict__ bk,
              const float* __restrict__ bv,
              unsigned short* __restrict__ Qo,
              unsigned short* __restrict__ Ko,
              unsigned short* __restrict__ Vto) {
    const int K = HID_;
    const int tid  = threadIdx.x;
    const int lane = tid & 63;
    const int wid  = tid >> 6;
    const int wr   = wid >> 1;
    const int wc   = wid & 1;
    const int l16  = lane & 15;
    const int l4   = lane >> 4;

    const int row0 = blockIdx.y * 128;
    const int col0 = blockIdx.x * 128;

    __shared__ unsigned short As[128 * 32];
    __shared__ unsigned short Bs[128 * 32];

    f32x4 acc[4][4] = {};

    const int srow = tid >> 2;
    const int scol = (tid & 3) * 8;
    const unsigned short* Ag = A + (size_t)(row0 + srow) * K + scol;
    const unsigned short* Bg = B + (size_t)(col0 + srow) * K + scol;
    unsigned short* AsW = As + wid * 512;
    unsigned short* BsW = Bs + wid * 512;

    const unsigned short* AsR = As + (size_t)(wr * 64 + l16) * 32 + l4 * 8;
    const unsigned short* BsR = Bs + (size_t)(wc * 64 + l16) * 32 + l4 * 8;

    for (int k0 = 0; k0 < K; k0 += 32) {
        __syncthreads();
        gld_lds16(AsW,        Ag + k0);
        gld_lds16(AsW + 2048, Ag + (size_t)64 * K + k0);
        gld_lds16(BsW,        Bg + k0);
        gld_lds16(BsW + 2048, Bg + (size_t)64 * K + k0);
        __syncthreads();

        bf16x8 af[4], bfr[4];
#pragma unroll
        for (int i = 0; i < 4; ++i)
            af[i] = *reinterpret_cast<const bf16x8*>(AsR + i * 16 * 32);
#pragma unroll
        for (int j = 0; j < 4; ++j)
            bfr[j] = *reinterpret_cast<const bf16x8*>(BsR + j * 16 * 32);
#pragma unroll
        for (int i = 0; i < 4; ++i)
#pragma unroll
            for (int j = 0; j < 4; ++j)
                acc[i][j] = __builtin_amdgcn_mfma_f32_16x16x32_bf16(
                    af[i], bfr[j], acc[i][j], 0, 0, 0);
    }

    // segment-uniform epilogue
    const int seg = col0 >> 11;                       // 0=Q 1=K 2=V
    const float* bias = (seg == 0) ? bq : (seg == 1) ? bk : bv;
    const int wrow0 = row0 + wr * 64;
    const int wcol0 = (col0 & (HID_ - 1)) + wc * 64;  // local col in segment

#pragma unroll
    for (int j = 0; j < 4; ++j) {
        const int col = wcol0 + j * 16 + l16;
        const float bvv = bias[col];
#pragma unroll
        for (int i = 0; i < 4; ++i) {
#pragma unroll
            for (int r = 0; r < 4; ++r) {
                const int row = wrow0 + i * 16 + l4 * 4 + r;
                const float v = acc[i][j][r] + bvv;
                if (seg == 0) {
                    Qo[(size_t)row * HID_ + col] = f32_to_bf16(v);
                } else if (seg == 1) {
                    Ko[(size_t)row * HID_ + col] = f32_to_bf16(v);
                } else {  // V^T: row=(b,s), col=(h,d) -> Vt[((b*NH+h)*HD+d)*SEQ+s]
                    const int b = row >> 11, s = row & (SEQ - 1);
                    const int h = col >> 7,  d = col & (HD_ - 1);
                    Vto[((size_t)((b * NH_ + h) * HD_ + d)) * SEQ + s] = f32_to_bf16(v);
                }
            }
        }
    }
}

// ---------------------------------------------------------------------------
// O-projection GEMM: out_f32[M,N] = A[M,K] * B[N,K]^T + bias[N]
// (m97 structure, unchanged from round 4)
// ---------------------------------------------------------------------------
__global__ __launch_bounds__(256)
void gemm_out(const unsigned short* __restrict__ A,
              const unsigned short* __restrict__ B,
              const float* __restrict__ bias,
              float* __restrict__ Cout,
              int M, int N, int K) {
    const int tid  = threadIdx.x;
    const int lane = tid & 63;
    const int wid  = tid >> 6;
    const int wr   = wid >> 1;
    const int wc   = wid & 1;
    const int l16  = lane & 15;
    const int l4   = lane >> 4;

    const int row0 = blockIdx.y * 128;
    const int col0 = blockIdx.x * 128;

    __shared__ unsigned short As[128 * 32];
    __shared__ unsigned short Bs[128 * 32];

    f32x4 acc[4][4] = {};

    const int srow = tid >> 2;
    const int scol = (tid & 3) * 8;
    const unsigned short* Ag = A + (size_t)(row0 + srow) * K + scol;
    const unsigned short* Bg = B + (size_t)(col0 + srow) * K + scol;
    unsigned short* AsW = As + wid * 512;
    unsigned short* BsW = Bs + wid * 512;

    const unsigned short* AsR = As + (size_t)(wr * 64 + l16) * 32 + l4 * 8;
    const unsigned short* BsR = Bs + (size_t)(wc * 64 + l16) * 32 + l4 * 8;

    for (int k0 = 0; k0 < K; k0 += 32) {
        __syncthreads();
        gld_lds16(AsW,        Ag + k0);
        gld_lds16(AsW + 2048, Ag + (size_t)64 * K + k0);
        gld_lds16(BsW,        Bg + k0);
        gld_lds16(BsW + 2048, Bg + (size_t)64 * K + k0);
        __syncthreads();

        bf16x8 af[4], bfr[4];
#pragma unroll
        for (int i = 0; i < 4; ++i)
            af[i] = *reinterpret_cast<const bf16x8*>(AsR + i * 16 * 32);
#pragma unroll
        for (int j = 0; j < 4; ++j)
            bfr[j] = *reinterpret_cast<const bf16x8*>(BsR + j * 16 * 32);
#pragma unroll
        for (int i = 0; i < 4; ++i)
#pragma unroll
            for (int j = 0; j < 4; ++j)
                acc[i][j] = __builtin_amdgcn_mfma_f32_16x16x32_bf16(
                    af[i], bfr[j], acc[i][j], 0, 0, 0);
    }

    const int wrow0 = row0 + wr * 64;
    const int wcol0 = col0 + wc * 64;
#pragma unroll
    for (int j = 0; j < 4; ++j) {
        const int col = wcol0 + j * 16 + l16;
        const float bv = bias[col];
#pragma unroll
        for (int i = 0; i < 4; ++i) {
#pragma unroll
            for (int r = 0; r < 4; ++r) {
                const int row = wrow0 + i * 16 + l4 * 4 + r;
                Cout[(size_t)row * N + col] = acc[i][j][r] + bv;
            }
        }
    }
}

// ---------------------------------------------------------------------------
// Causal flash attention, v4 (unchanged from round 4): cooperative 4-wave
// blocks, 64 q rows / block; K/V^T tiles double-buffered in LDS via
// global_load_lds, XOR-swizzled; grid (B*NH, SEQ/64), heavy-first LPT.
// ---------------------------------------------------------------------------
__global__ __launch_bounds__(256, 2)
void attn_fwd(const unsigned short* __restrict__ Qm,
              const unsigned short* __restrict__ Km,
              const unsigned short* __restrict__ Vt,
              unsigned short* __restrict__ Om) {
    const int tid  = threadIdx.x;
    const int lane = tid & 63;
    const int wq   = tid >> 6;
    const int l16  = lane & 15;
    const int l4   = lane >> 4;

    const int bh = blockIdx.x;
    const int qt = (int)gridDim.y - 1 - (int)blockIdx.y;
    const int b  = bh >> 4;
    const int h  = bh & (NH_ - 1);

    const int qbase  = qt * 64 + wq * 16;
    const int ntiles = qt + 1;

    __shared__ unsigned short Ks[2][64 * 128];
    __shared__ unsigned short Vs[2][128 * 64];
    __shared__ unsigned short plds[4][16][68];

    const unsigned short* Kbh = Km + ((size_t)b * SEQ) * HID_ + h * HD_;
    const unsigned short* Vbh = Vt + (size_t)bh * HD_ * SEQ;

    auto stage = [&](int buf, int t) {
        const int kv0 = t * 64;
        {
            const int rl = lane >> 4;
            const int ck = lane & 15;
#pragma unroll
            for (int j = 0; j < 4; ++j) {
                const int r  = wq * 16 + 4 * j + rl;
                const int lc = ck ^ (r & 7);
                gld_lds16(&Ks[buf][(wq * 16 + 4 * j) * 128],
                          Kbh + (size_t)(kv0 + r) * HID_ + lc * 8);
            }
        }
        {
            const int rl = lane >> 3;
            const int ck = lane & 7;
#pragma unroll
            for (int j = 0; j < 4; ++j) {
                const int r  = wq * 32 + 8 * j + rl;
                const int lc = ck ^ (r & 7);
                gld_lds16(&Vs[buf][(wq * 32 + 8 * j) * 64],
                          Vbh + (size_t)r * SEQ + kv0 + lc * 8);
            }
        }
    };

    stage(0, 0);
    const unsigned short* Qbase =
        Qm + ((size_t)(b * SEQ + qbase + l16)) * HID_ + h * HD_ + l4 * 8;
    bf16x8 qf[4];
#pragma unroll
    for (int kb = 0; kb < 4; ++kb)
        qf[kb] = *reinterpret_cast<const bf16x8*>(Qbase + kb * 32);

    float mrow[4], lrow[4];
#pragma unroll
    for (int r = 0; r < 4; ++r) { mrow[r] = -__builtin_inff(); lrow[r] = 0.f; }
    f32x4 acc[8] = {};

    const float scale = 0.08838834764831845f;  // 1/sqrt(128)

    int buf = 0;
    for (int t = 0; t < ntiles; ++t) {
        __syncthreads();
        if (t + 1 < ntiles) stage(buf ^ 1, t + 1);

        const unsigned short* Kb0 = &Ks[buf][0];
        const unsigned short* Vb0 = &Vs[buf][0];
        const int kv0 = t * 64;
        const int sw  = l16 & 7;

        f32x4 sc[4];
#pragma unroll
        for (int ct = 0; ct < 4; ++ct) {
            f32x4 c = {};
#pragma unroll
            for (int kb = 0; kb < 4; ++kb) {
                bf16x8 kf = *reinterpret_cast<const bf16x8*>(
                    Kb0 + (ct * 16 + l16) * 128 + ((kb * 4 + l4) ^ sw) * 8);
                c = __builtin_amdgcn_mfma_f32_16x16x32_bf16(qf[kb], kf, c, 0, 0, 0);
            }
            sc[ct] = c;
        }

        if (t == ntiles - 1) {
#pragma unroll
            for (int ct = 0; ct < 4; ++ct) {
                const int col = kv0 + ct * 16 + l16;
#pragma unroll
                for (int r = 0; r < 4; ++r) {
                    float v = sc[ct][r] * scale;
                    const int qrow = qbase + l4 * 4 + r;
                    if (col > qrow) v = -__builtin_inff();
                    sc[ct][r] = v;
                }
            }
        } else {
#pragma unroll
            for (int ct = 0; ct < 4; ++ct)
#pragma unroll
                for (int r = 0; r < 4; ++r)
                    sc[ct][r] *= scale;
        }

        float tmax[4];
#pragma unroll
        for (int r = 0; r < 4; ++r) {
            float v = fmaxf(fmaxf(sc[0][r], sc[1][r]), fmaxf(sc[2][r], sc[3][r]));
#pragma unroll
            for (int off = 8; off >= 1; off >>= 1)
                v = fmaxf(v, __shfl_xor(v, off, 64));
            tmax[r] = v;
        }

        float alpha[4], rs[4];
#pragma unroll
        for (int r = 0; r < 4; ++r) {
            const float mn = fmaxf(mrow[r], tmax[r]);
            alpha[r] = __expf(mrow[r] - mn);
            mrow[r] = mn;
            rs[r] = 0.f;
        }

#pragma unroll
        for (int ct = 0; ct < 4; ++ct) {
#pragma unroll
            for (int r = 0; r < 4; ++r) {
                const float p = __expf(sc[ct][r] - mrow[r]);
                rs[r] += p;
                plds[wq][l4 * 4 + r][ct * 16 + l16] = f32_to_bf16(p);
            }
        }

#pragma unroll
        for (int r = 0; r < 4; ++r) {
#pragma unroll
            for (int off = 8; off >= 1; off >>= 1)
                rs[r] += __shfl_xor(rs[r], off, 64);
            lrow[r] = lrow[r] * alpha[r] + rs[r];
        }

#pragma unroll
        for (int dt = 0; dt < 8; ++dt)
#pragma unroll
            for (int r = 0; r < 4; ++r)
                acc[dt][r] *= alpha[r];

        asm volatile("s_waitcnt lgkmcnt(0)" ::: "memory");
        bf16x8 pf[2];
#pragma unroll
        for (int ks = 0; ks < 2; ++ks)
            pf[ks] = *reinterpret_cast<const bf16x8*>(&plds[wq][l16][ks * 32 + l4 * 8]);
#pragma unroll
        for (int dt = 0; dt < 8; ++dt) {
#pragma unroll
            for (int ks = 0; ks < 2; ++ks) {
                bf16x8 vf = *reinterpret_cast<const bf16x8*>(
                    Vb0 + (dt * 16 + l16) * 64 + ((ks * 4 + l4) ^ sw) * 8);
                acc[dt] = __builtin_amdgcn_mfma_f32_16x16x32_bf16(pf[ks], vf, acc[dt], 0, 0, 0);
            }
        }

        buf ^= 1;
    }

    unsigned short* Ob = Om + ((size_t)(b * SEQ + qbase)) * HID_ + h * HD_;
#pragma unroll
    for (int dt = 0; dt < 8; ++dt) {
#pragma unroll
        for (int r = 0; r < 4; ++r) {
            const int qrow = l4 * 4 + r;
            const float v = acc[dt][r] / lrow[r];
            Ob[(size_t)qrow * HID_ + dt * 16 + l16] = f32_to_bf16(v);
        }
    }
}

// ---------------------------------------------------------------------------
extern "C" void kernel_launch(void* const* d_in, const int* in_sizes, int n_in,
                              void* d_out, int out_size, void* d_ws, size_t ws_size,
                              hipStream_t stream) {
    const float* X  = (const float*)d_in[0];
    const float* Wq = (const float*)d_in[1];
    const float* bq = (const float*)d_in[2];
    const float* Wk = (const float*)d_in[3];
    const float* bk = (const float*)d_in[4];
    const float* Wv = (const float*)d_in[5];
    const float* bv = (const float*)d_in[6];
    const float* Wo = (const float*)d_in[7];
    const float* bo = (const float*)d_in[8];
    float* out = (float*)d_out;

    const size_t MK = (size_t)BATCH * SEQ * HID_;   // 8388608
    const size_t WK = (size_t)HID_ * HID_;          // 4194304

    unsigned short* ws  = (unsigned short*)d_ws;
    unsigned short* Xb  = ws;
    unsigned short* Wqb = Xb  + MK;   // Wq, Wk, Wv contiguous -> fused B
    unsigned short* Wkb = Wqb + WK;
    unsigned short* Wvb = Wkb + WK;
    unsigned short* Wob = Wvb + WK;
    unsigned short* Qb  = Wob + WK;
    unsigned short* Kb  = Qb  + MK;
    unsigned short* Vtb = Kb  + MK;
    unsigned short* AOb = Vtb + MK;

    auto cvt = [&](const float* src, unsigned short* dst, size_t n) {
        int n4 = (int)(n / 4);
        cvt_f32_bf16<<<(n4 + 255) / 256, 256, 0, stream>>>(src, dst, n4);
    };
    cvt(X,  Xb,  MK);
    cvt(Wq, Wqb, WK);
    cvt(Wk, Wkb, WK);
    cvt(Wv, Wvb, WK);
    cvt(Wo, Wob, WK);

    const int M = BATCH * SEQ;   // 4096

    // Fused QKV projection: N = 6144, grid (48, 32) = 1536 blocks
    gemm_qkv<<<dim3(3 * HID_ / 128, M / 128), 256, 0, stream>>>(
        Xb, Wqb, bq, bk, bv, Qb, Kb, Vtb);

    attn_fwd<<<dim3(BATCH * NH_, SEQ / 64), 256, 0, stream>>>(Qb, Kb, Vtb, AOb);

    gemm_out<<<dim3(HID_ / 128, M / 128), 256, 0, stream>>>(
        AOb, Wob, bo, out, M, HID_, HID_);
}